// Round 1
// baseline (357.326 us; speedup 1.0000x reference)
//
#include <hip/hip_runtime.h>

// GCN on MI355X (gfx950). n=100000, 1.6M edges, D 128/128/64.
// Round 10: column-locality for the gather-bound SpMM kernels.
//  - part2 rewritten: 256-row buckets (NBUCK=392), edges staged in REGISTERS
//    (18 int2/thread), 13 column-range passes (col>>13) scatter via LDS
//    row-cursors into an LDS output image, then coalesced stream-out.
//    => every row's CSR edge list is sorted by coarse column bucket.
//  - Effect: all concurrently-resident spmm blocks sweep H front-to-back in
//    loose lockstep -> gather window ~2-6 MB instead of 25.6 MB -> L2/L3 hits.
//  - Also fixes part2's old random 8B global writes (now coalesced) and its
//    block-parallelism (196 -> 392 blocks).
// Downstream spmm_gemm / spmm_out unchanged (same CSR format, new edge order).
// Pipeline: wcvt -> K1[part1||gemm0] -> part2 -> F1 -> F2 -> spmm_out.

typedef unsigned int u32;
typedef unsigned short u16;
typedef __attribute__((ext_vector_type(8))) short bf16x8;
typedef __attribute__((ext_vector_type(4))) float f32x4;

constexpr int NN = 100000;
constexpr int NE = 1600000;
constexpr int PAD = 100352;            // 392 * 256
constexpr int NBUCK = 392;             // buckets of 256 rows
constexpr int BCAP = 4608;             // per-bucket capacity (mean 4082, +8 sigma)
constexpr int EPB = 4096;              // edges per part1 block
constexpr int P1B = (NE + EPB - 1) / EPB;   // 391 part1 blocks
constexpr int G0B = (NN + 63) / 64;         // 1563 gemm0 blocks
constexpr int EPT = BCAP / 256;        // 18 edges staged per thread in part2
constexpr int NPASS = 13;              // col passes of 8192 cols (99999>>13 = 12)

__device__ __forceinline__ u16 f2bf(float f) {   // RNE round to bf16
    u32 x = __float_as_uint(f);
    x += 0x7fffu + ((x >> 16) & 1u);
    return (u16)(x >> 16);
}

// ---------------------------------------------------------------------------
// Weight fp32 -> bf16 in B-fragment order; blocks 0/1 also zero bcur.
// ---------------------------------------------------------------------------
__device__ __forceinline__ void wfrag_one(const float* __restrict__ W,
                                          u16* __restrict__ Wf, int total, int i)
{
    if (i < total) {
        const int j    = i & 7;
        const int lane = (i >> 3) & 63;
        const int kc   = (i >> 9) & 3;
        const int ct   = i >> 11;
        const int src  = (ct * 16 + (lane & 15)) * 128 + kc * 32 + (lane >> 4) * 8 + j;
        Wf[i] = f2bf(W[src]);
    }
}

__global__ __launch_bounds__(256)
void wcvt_kernel(const float* __restrict__ W0, const float* __restrict__ W1,
                 const float* __restrict__ W2, u16* __restrict__ wf0,
                 u16* __restrict__ wf1, u16* __restrict__ wf2,
                 int* __restrict__ bcur)
{
    const int i = blockIdx.x * 256 + threadIdx.x;
    if (i < 512) bcur[i] = 0;
    wfrag_one(W0, wf0, 128 * 128, i);
    wfrag_one(W1, wf1, 128 * 128, i);
    wfrag_one(W2, wf2, 64 * 128, i);
}

// ---------------------------------------------------------------------------
// K1: blocks [0, P1B) = part1 (bucket partition, streaming two-pass);
//     blocks [P1B, P1B+G0B) = gemm0 (t0 = x @ W0^T, bf16 MFMA).
// Shared LDS buffer sized for the gemm branch (17408 B).
// ---------------------------------------------------------------------------
__global__ __launch_bounds__(256)
void k1_kernel(const float* __restrict__ x, const u16* __restrict__ Wf,
               u16* __restrict__ Cb,
               const int* __restrict__ erow, const int* __restrict__ ecol,
               const float* __restrict__ eval, int* __restrict__ bcur,
               int2* __restrict__ part)
{
    __shared__ u16 smem[64 * 136];     // gemm: sA/sC; part1: shist/sbase
    const int tid = threadIdx.x;

    if ((int)blockIdx.x < P1B) {
        // ---------------- part1 branch ----------------
        int* shist = (int*)smem;
        int* sbase = shist + NBUCK;
        for (int i = tid; i < NBUCK; i += 256) shist[i] = 0;
        __syncthreads();

        const int base = blockIdx.x * EPB;
        #pragma unroll
        for (int j = 0; j < EPB / 256; ++j) {
            const int e = base + j * 256 + tid;
            if (e < NE) atomicAdd(&shist[erow[e] >> 8], 1);
        }
        __syncthreads();
        for (int i = tid; i < NBUCK; i += 256) {
            const int c = shist[i];
            sbase[i] = c ? atomicAdd(&bcur[i], c) : 0;
            shist[i] = 0;
        }
        __syncthreads();
        #pragma unroll
        for (int j = 0; j < EPB / 256; ++j) {
            const int e = base + j * 256 + tid;
            if (e < NE) {
                const int r = erow[e];
                const int b = r >> 8;
                const int rk = atomicAdd(&shist[b], 1);
                part[(size_t)b * BCAP + sbase[b] + rk] =
                    make_int2(((r & 255) << 17) | ecol[e], __float_as_int(eval[e]));
            }
        }
        return;
    }

    // ---------------- gemm0 branch ----------------
    constexpr int RS   = 136;
    constexpr int PADW = 136;          // DO=128 + 8
    u16* sA = smem;
    u16* sC = smem;
    const int w    = tid >> 6;
    const int lane = tid & 63;
    const int m    = lane & 15;
    const int q    = lane >> 4;
    const int rowBase = ((int)blockIdx.x - P1B) * 64;

    #pragma unroll
    for (int i = 0; i < 8; ++i) {
        const int g = (i * 256 + tid) * 4;
        const int r = g >> 7, c = g & 127;
        float4 v = make_float4(0.f, 0.f, 0.f, 0.f);
        if (rowBase + r < NN) v = *(const float4*)(x + (size_t)(rowBase + r) * 128 + c);
        u16* d = &sA[r * RS + c];
        d[0] = f2bf(v.x); d[1] = f2bf(v.y); d[2] = f2bf(v.z); d[3] = f2bf(v.w);
    }
    __syncthreads();

    bf16x8 afrag[4];
    #pragma unroll
    for (int kc = 0; kc < 4; ++kc)
        afrag[kc] = *(const bf16x8*)&sA[(w * 16 + m) * RS + kc * 32 + q * 8];
    __syncthreads();

    #pragma unroll
    for (int ct = 0; ct < 8; ++ct) {
        f32x4 acc = {0.f, 0.f, 0.f, 0.f};
        #pragma unroll
        for (int kc = 0; kc < 4; ++kc) {
            const bf16x8 b = *(const bf16x8*)(Wf + (((ct * 4 + kc) * 64) + lane) * 8);
            acc = __builtin_amdgcn_mfma_f32_16x16x32_bf16(afrag[kc], b, acc, 0, 0, 0);
        }
        #pragma unroll
        for (int r = 0; r < 4; ++r)
            sC[(w * 16 + q * 4 + r) * PADW + ct * 16 + m] = f2bf(acc[r]);
    }
    __syncthreads();

    const int g    = lane >> 2;
    const int cb   = (lane & 3) * 32;
    const int grow = rowBase + w * 16 + g;
    if (grow < NN) {
        #pragma unroll
        for (int i = 0; i < 4; ++i) {
            const int4 v = *(const int4*)&sC[(w * 16 + g) * PADW + cb + i * 8];
            *(int4*)(Cb + (size_t)grow * 128 + cb + i * 8) = v;
        }
    }
}

// ---------------------------------------------------------------------------
// part2 (round 10): per 256-row bucket -
//   gb = prefix over bcur; stage bucket edges into REGISTERS (18/thread);
//   per-row histogram + scan -> offs + LDS row cursors; 13 column-range
//   passes scatter into LDS output image (=> per-row col-sorted order);
//   coalesced stream-out to pce.
// ---------------------------------------------------------------------------
__global__ __launch_bounds__(256)
void part2_kernel(const int* __restrict__ bcur, const int2* __restrict__ part,
                  int* __restrict__ offs, int2* __restrict__ pce)
{
    __shared__ int scnt[256];
    __shared__ int rowoff[256];
    __shared__ int sdata[256];
    __shared__ int2 sout[BCAP];        // 36864 B staged output image
    const int b = blockIdx.x;
    const int tid = threadIdx.x;

    const int cnt = bcur[b];
    const int2* src = part + (size_t)b * BCAP;

    // stage this bucket's edges into registers (coalesced, strided by 256)
    int2 ed[EPT];
    #pragma unroll
    for (int j = 0; j < EPT; ++j) {
        const int idx = j * 256 + tid;
        ed[j] = (idx < cnt) ? src[idx] : make_int2(-1, 0);
    }

    // global prefix: gb = sum bcur[0..b-1]
    int partial = 0;
    for (int i = tid; i < b; i += 256) partial += bcur[i];
    sdata[tid] = partial;
    __syncthreads();
    #pragma unroll
    for (int off = 128; off > 0; off >>= 1) {
        if (tid < off) sdata[tid] += sdata[tid + off];
        __syncthreads();
    }
    const int gb = sdata[0];
    __syncthreads();

    // per-row histogram (256 rows in this bucket)
    scnt[tid] = 0;
    __syncthreads();
    #pragma unroll
    for (int j = 0; j < EPT; ++j)
        if (ed[j].x >= 0) atomicAdd(&scnt[((u32)ed[j].x) >> 17], 1);
    __syncthreads();

    // inclusive scan over 256 row counts -> exclusive offsets
    const int c = scnt[tid];
    sdata[tid] = c;
    __syncthreads();
    #pragma unroll
    for (int off = 1; off < 256; off <<= 1) {
        const int val = (tid >= off) ? sdata[tid - off] : 0;
        __syncthreads();
        sdata[tid] += val;
        __syncthreads();
    }
    const int excl = sdata[tid] - c;
    rowoff[tid] = excl;                    // local cursor into sout
    offs[b * 256 + tid] = gb + excl;       // global CSR offset
    __syncthreads();

    // 13 column-range passes: emit edges in coarse col-sorted order per row.
    // (sentinel x=-1 has col field 0x1FFFF -> pass 15, never matched)
    for (int p = 0; p < NPASS; ++p) {
        #pragma unroll
        for (int j = 0; j < EPT; ++j) {
            const int key = ed[j].x & 0x1FFFF;
            if ((key >> 13) == p) {
                const int rl  = ((u32)ed[j].x) >> 17;
                const int pos = atomicAdd(&rowoff[rl], 1);
                sout[pos] = make_int2(key, ed[j].y);
            }
        }
        __syncthreads();
    }

    // coalesced stream-out
    #pragma unroll
    for (int j = 0; j < EPT; ++j) {
        const int idx = j * 256 + tid;
        if (idx < cnt) pce[(size_t)gb + idx] = sout[idx];
    }
}

// ---------------------------------------------------------------------------
// Gather helpers (bf16 rows, fp32 accumulate).
// ---------------------------------------------------------------------------
template<int LPC>
__device__ __forceinline__ void load_row(const u16* p, u32* u) {
    if constexpr (LPC == 8) {
        const uint4 t = *(const uint4*)p;
        u[0] = t.x; u[1] = t.y; u[2] = t.z; u[3] = t.w;
    } else {
        const uint2 t = *(const uint2*)p;
        u[0] = t.x; u[1] = t.y;
    }
}

template<int LPC>
__device__ __forceinline__ void fma_row(float v, const u32* u, float* a) {
    #pragma unroll
    for (int j = 0; j < LPC / 2; ++j) {
        a[2*j]   = fmaf(v, __uint_as_float(u[j] << 16),         a[2*j]);
        a[2*j+1] = fmaf(v, __uint_as_float(u[j] & 0xffff0000u), a[2*j+1]);
    }
}

// ---------------------------------------------------------------------------
// Fused SpMM+GEMM: gather 16 rows of A*t -> relu(+residual) -> LDS A-tile
// -> mfma vs fragment-ordered Wf -> coalesced C store.
// MODE 1 also writes relu'd rows (h1) to Hout for the later residual.
// ---------------------------------------------------------------------------
template<int DO, int MODE>
__global__ __launch_bounds__(256)
void spmm_gemm(const int* __restrict__ offs, const int2* __restrict__ pce,
               const u16* __restrict__ Hb, const u16* __restrict__ Wf,
               const u16* __restrict__ Res, u16* __restrict__ Cb,
               u16* __restrict__ Hout)
{
    constexpr int RS   = 136;
    constexpr int PADW = DO + 8;
    __shared__ u16 smem[16 * 136];
    const int tid = threadIdx.x;
    const int ln  = tid & 15;
    const int rl  = tid >> 4;
    const int row = blockIdx.x * 16 + rl;

    const int s = offs[row];
    const int t = offs[row + 1];
    const u16* hbase = Hb + ln * 8;

    float a0[8], a1[8];
    #pragma unroll
    for (int j = 0; j < 8; ++j) { a0[j] = 0.f; a1[j] = 0.f; }

    int e = s;
    for (; e + 1 < t; e += 2) {
        const int2 e0 = pce[e];
        const int2 e1 = pce[e + 1];
        u32 u0[4], u1[4];
        load_row<8>(hbase + (size_t)e0.x * 128, u0);
        load_row<8>(hbase + (size_t)e1.x * 128, u1);
        fma_row<8>(__int_as_float(e0.y), u0, a0);
        fma_row<8>(__int_as_float(e1.y), u1, a1);
    }
    if (e < t) {
        const int2 e0 = pce[e];
        u32 u0[4];
        load_row<8>(hbase + (size_t)e0.x * 128, u0);
        fma_row<8>(__int_as_float(e0.y), u0, a0);
    }
    #pragma unroll
    for (int j = 0; j < 8; ++j) a0[j] = fmaxf(a0[j] + a1[j], 0.f);

    if constexpr (MODE == 2) {
        u32 r[4];
        load_row<8>(Res + (size_t)row * 128 + ln * 8, r);
        #pragma unroll
        for (int j = 0; j < 4; ++j) {
            a0[2*j]   += __uint_as_float(r[j] << 16);
            a0[2*j+1] += __uint_as_float(r[j] & 0xffff0000u);
        }
    }
    u32 o[4];
    #pragma unroll
    for (int j = 0; j < 4; ++j)
        o[j] = (u32)f2bf(a0[2*j]) | ((u32)f2bf(a0[2*j+1]) << 16);
    const uint4 packed = make_uint4(o[0], o[1], o[2], o[3]);
    *(uint4*)&smem[rl * RS + ln * 8] = packed;
    if constexpr (MODE == 1)
        *(uint4*)(Hout + (size_t)row * 128 + ln * 8) = packed;
    __syncthreads();

    constexpr int TPW = DO / 64;
    const int w    = tid >> 6;
    const int lane = tid & 63;
    const int m    = lane & 15;
    const int q    = lane >> 4;

    bf16x8 afrag[4];
    #pragma unroll
    for (int kc = 0; kc < 4; ++kc)
        afrag[kc] = *(const bf16x8*)&smem[m * RS + kc * 32 + q * 8];

    f32x4 acc[TPW];
    #pragma unroll
    for (int tw = 0; tw < TPW; ++tw) {
        const int ct = w * TPW + tw;
        acc[tw] = (f32x4){0.f, 0.f, 0.f, 0.f};
        #pragma unroll
        for (int kc = 0; kc < 4; ++kc) {
            const bf16x8 b = *(const bf16x8*)(Wf + (((ct * 4 + kc) * 64) + lane) * 8);
            acc[tw] = __builtin_amdgcn_mfma_f32_16x16x32_bf16(afrag[kc], b, acc[tw], 0, 0, 0);
        }
    }
    __syncthreads();

    #pragma unroll
    for (int tw = 0; tw < TPW; ++tw) {
        const int ct = w * TPW + tw;
        #pragma unroll
        for (int r = 0; r < 4; ++r)
            smem[(q * 4 + r) * PADW + ct * 16 + m] = f2bf(acc[tw][r]);
    }
    __syncthreads();

    if (DO == 128 || tid < 128) {
        const int g = tid * 8;
        const int r = g / DO;
        const int c = g % DO;
        const int4 v = *(const int4*)&smem[r * PADW + c];
        *(int4*)(Cb + ((size_t)blockIdx.x * 16 + r) * DO + c) = v;
    }
}

// ---------------------------------------------------------------------------
// Final CSR SpMM (layer 3): gather t2 (D=64), write fp32 out.
// ---------------------------------------------------------------------------
__global__ __launch_bounds__(256)
void spmm_out(const int* __restrict__ offs, const int2* __restrict__ pce,
              const u16* __restrict__ Hb, float* __restrict__ Y)
{
    const int ln  = threadIdx.x & 15;
    const int row = blockIdx.x * 16 + (threadIdx.x >> 4);
    if (row >= NN) return;
    const int s = offs[row];
    const int t = offs[row + 1];
    const u16* hbase = Hb + ln * 4;

    float a0[4], a1[4];
    #pragma unroll
    for (int j = 0; j < 4; ++j) { a0[j] = 0.f; a1[j] = 0.f; }

    int e = s;
    for (; e + 1 < t; e += 2) {
        const int2 e0 = pce[e];
        const int2 e1 = pce[e + 1];
        u32 u0[2], u1[2];
        load_row<4>(hbase + (size_t)e0.x * 64, u0);
        load_row<4>(hbase + (size_t)e1.x * 64, u1);
        fma_row<4>(__int_as_float(e0.y), u0, a0);
        fma_row<4>(__int_as_float(e1.y), u1, a1);
    }
    if (e < t) {
        const int2 e0 = pce[e];
        u32 u0[2];
        load_row<4>(hbase + (size_t)e0.x * 64, u0);
        fma_row<4>(__int_as_float(e0.y), u0, a0);
    }
    #pragma unroll
    for (int j = 0; j < 4; ++j) a0[j] += a1[j];
    *(float4*)(Y + (size_t)row * 64 + ln * 4) = make_float4(a0[0], a0[1], a0[2], a0[3]);
}

extern "C" void kernel_launch(void* const* d_in, const int* in_sizes, int n_in,
                              void* d_out, int out_size, void* d_ws, size_t ws_size,
                              hipStream_t stream) {
    const float* x    = (const float*)d_in[0];
    const int*   erow = (const int*)  d_in[1];
    const int*   ecol = (const int*)  d_in[2];
    const float* eval = (const float*)d_in[3];
    const float* W0   = (const float*)d_in[4];
    const float* W1   = (const float*)d_in[5];
    const float* W2   = (const float*)d_in[6];
    float* out = (float*)d_out;

    char* p = (char*)d_ws;
    const size_t BUFB = (size_t)NN * 128 * sizeof(u16);   // 25.6 MB
    u16* t0b  = (u16*)p;  p += BUFB;     // t0; reused for t2 (t0 dead by then)
    u16* t1b  = (u16*)p;  p += BUFB;
    u16* h1b  = (u16*)p;  p += BUFB;
    u16* wf0  = (u16*)p;  p += 128 * 128 * 2;
    u16* wf1  = (u16*)p;  p += 128 * 128 * 2;
    u16* wf2  = (u16*)p;  p += 64 * 128 * 2;
    int* bcur   = (int*)p; p += 512 * 4;
    int* offs   = (int*)p; p += ((size_t)PAD + 256) * 4;
    int2* part  = (int2*)p; p += (size_t)NBUCK * BCAP * 8;  // 14.45 MB
    int2* pce   = (int2*)p;                                 // 12.8 MB

    const dim3 blk(256);
    const int rowBlocks = NN / 16;     // 6250

    // wcvt (also zeroes bcur) -> K1 [part1 || gemm0] -> part2 -> F1 -> F2 -> out
    wcvt_kernel<<<64, blk, 0, stream>>>(W0, W1, W2, wf0, wf1, wf2, bcur);
    k1_kernel  <<<P1B + G0B, blk, 0, stream>>>(x, wf0, t0b, erow, ecol, eval, bcur, part);
    part2_kernel<<<NBUCK, blk, 0, stream>>>(bcur, part, offs, pce);
    spmm_gemm<128, 1><<<rowBlocks, blk, 0, stream>>>(offs, pce, t0b, wf1, nullptr, t1b, h1b);
    spmm_gemm<64, 2><<<rowBlocks, blk, 0, stream>>>(offs, pce, t1b, wf2, h1b, t0b, nullptr);
    spmm_out<<<rowBlocks, blk, 0, stream>>>(offs, pce, t0b, out);
}

// Round 2
// 329.263 us; speedup vs baseline: 1.0852x; 1.0852x over previous
//
#include <hip/hip_runtime.h>

// GCN on MI355X (gfx950). n=100000, 1.6M edges, D 128/128/64.
// Round 11: latency-hiding in the gather kernels + cheap single-pass sort.
//  - spmm_gemm / spmm_out inner loops unrolled to 4 edges in flight
//    (4 independent 256B/128B row loads issued before the FMA block).
//    VGPR stays <=64 so occupancy is unchanged; MLP doubles.
//  - part2: 13-pass column-bucket scatter replaced by a single-pass counting
//    sort on combined key (row*13 + colbucket): LDS histogram (3328 ctrs) ->
//    per-row scan -> ONE scatter pass -> coalesced stream-out. Same edge
//    order (col-bucket-sorted within row) at ~1/3 the cost.
// Pipeline: wcvt -> K1[part1||gemm0] -> part2 -> F1 -> F2 -> spmm_out.

typedef unsigned int u32;
typedef unsigned short u16;
typedef __attribute__((ext_vector_type(8))) short bf16x8;
typedef __attribute__((ext_vector_type(4))) float f32x4;

constexpr int NN = 100000;
constexpr int NE = 1600000;
constexpr int PAD = 100352;            // 392 * 256
constexpr int NBUCK = 392;             // buckets of 256 rows
constexpr int BCAP = 4608;             // per-bucket capacity (mean 4082, +8 sigma)
constexpr int EPB = 4096;              // edges per part1 block
constexpr int P1B = (NE + EPB - 1) / EPB;   // 391 part1 blocks
constexpr int G0B = (NN + 63) / 64;         // 1563 gemm0 blocks
constexpr int EPT = BCAP / 256;        // 18 edges staged per thread in part2
constexpr int NCB = 13;                // col buckets of 8192 (99999>>13 = 12)

__device__ __forceinline__ u16 f2bf(float f) {   // RNE round to bf16
    u32 x = __float_as_uint(f);
    x += 0x7fffu + ((x >> 16) & 1u);
    return (u16)(x >> 16);
}

// ---------------------------------------------------------------------------
// Weight fp32 -> bf16 in B-fragment order; also zeroes bcur.
// ---------------------------------------------------------------------------
__device__ __forceinline__ void wfrag_one(const float* __restrict__ W,
                                          u16* __restrict__ Wf, int total, int i)
{
    if (i < total) {
        const int j    = i & 7;
        const int lane = (i >> 3) & 63;
        const int kc   = (i >> 9) & 3;
        const int ct   = i >> 11;
        const int src  = (ct * 16 + (lane & 15)) * 128 + kc * 32 + (lane >> 4) * 8 + j;
        Wf[i] = f2bf(W[src]);
    }
}

__global__ __launch_bounds__(256)
void wcvt_kernel(const float* __restrict__ W0, const float* __restrict__ W1,
                 const float* __restrict__ W2, u16* __restrict__ wf0,
                 u16* __restrict__ wf1, u16* __restrict__ wf2,
                 int* __restrict__ bcur)
{
    const int i = blockIdx.x * 256 + threadIdx.x;
    if (i < 512) bcur[i] = 0;
    wfrag_one(W0, wf0, 128 * 128, i);
    wfrag_one(W1, wf1, 128 * 128, i);
    wfrag_one(W2, wf2, 64 * 128, i);
}

// ---------------------------------------------------------------------------
// K1: blocks [0, P1B) = part1 (bucket partition, streaming two-pass);
//     blocks [P1B, P1B+G0B) = gemm0 (t0 = x @ W0^T, bf16 MFMA).
// Shared LDS buffer sized for the gemm branch (17408 B).
// ---------------------------------------------------------------------------
__global__ __launch_bounds__(256)
void k1_kernel(const float* __restrict__ x, const u16* __restrict__ Wf,
               u16* __restrict__ Cb,
               const int* __restrict__ erow, const int* __restrict__ ecol,
               const float* __restrict__ eval, int* __restrict__ bcur,
               int2* __restrict__ part)
{
    __shared__ u16 smem[64 * 136];     // gemm: sA/sC; part1: shist/sbase
    const int tid = threadIdx.x;

    if ((int)blockIdx.x < P1B) {
        // ---------------- part1 branch ----------------
        int* shist = (int*)smem;
        int* sbase = shist + NBUCK;
        for (int i = tid; i < NBUCK; i += 256) shist[i] = 0;
        __syncthreads();

        const int base = blockIdx.x * EPB;
        #pragma unroll
        for (int j = 0; j < EPB / 256; ++j) {
            const int e = base + j * 256 + tid;
            if (e < NE) atomicAdd(&shist[erow[e] >> 8], 1);
        }
        __syncthreads();
        for (int i = tid; i < NBUCK; i += 256) {
            const int c = shist[i];
            sbase[i] = c ? atomicAdd(&bcur[i], c) : 0;
            shist[i] = 0;
        }
        __syncthreads();
        #pragma unroll
        for (int j = 0; j < EPB / 256; ++j) {
            const int e = base + j * 256 + tid;
            if (e < NE) {
                const int r = erow[e];
                const int b = r >> 8;
                const int rk = atomicAdd(&shist[b], 1);
                part[(size_t)b * BCAP + sbase[b] + rk] =
                    make_int2(((r & 255) << 17) | ecol[e], __float_as_int(eval[e]));
            }
        }
        return;
    }

    // ---------------- gemm0 branch ----------------
    constexpr int RS   = 136;
    constexpr int PADW = 136;          // DO=128 + 8
    u16* sA = smem;
    u16* sC = smem;
    const int w    = tid >> 6;
    const int lane = tid & 63;
    const int m    = lane & 15;
    const int q    = lane >> 4;
    const int rowBase = ((int)blockIdx.x - P1B) * 64;

    #pragma unroll
    for (int i = 0; i < 8; ++i) {
        const int g = (i * 256 + tid) * 4;
        const int r = g >> 7, c = g & 127;
        float4 v = make_float4(0.f, 0.f, 0.f, 0.f);
        if (rowBase + r < NN) v = *(const float4*)(x + (size_t)(rowBase + r) * 128 + c);
        u16* d = &sA[r * RS + c];
        d[0] = f2bf(v.x); d[1] = f2bf(v.y); d[2] = f2bf(v.z); d[3] = f2bf(v.w);
    }
    __syncthreads();

    bf16x8 afrag[4];
    #pragma unroll
    for (int kc = 0; kc < 4; ++kc)
        afrag[kc] = *(const bf16x8*)&sA[(w * 16 + m) * RS + kc * 32 + q * 8];
    __syncthreads();

    #pragma unroll
    for (int ct = 0; ct < 8; ++ct) {
        f32x4 acc = {0.f, 0.f, 0.f, 0.f};
        #pragma unroll
        for (int kc = 0; kc < 4; ++kc) {
            const bf16x8 b = *(const bf16x8*)(Wf + (((ct * 4 + kc) * 64) + lane) * 8);
            acc = __builtin_amdgcn_mfma_f32_16x16x32_bf16(afrag[kc], b, acc, 0, 0, 0);
        }
        #pragma unroll
        for (int r = 0; r < 4; ++r)
            sC[(w * 16 + q * 4 + r) * PADW + ct * 16 + m] = f2bf(acc[r]);
    }
    __syncthreads();

    const int g    = lane >> 2;
    const int cb   = (lane & 3) * 32;
    const int grow = rowBase + w * 16 + g;
    if (grow < NN) {
        #pragma unroll
        for (int i = 0; i < 4; ++i) {
            const int4 v = *(const int4*)&sC[(w * 16 + g) * PADW + cb + i * 8];
            *(int4*)(Cb + (size_t)grow * 128 + cb + i * 8) = v;
        }
    }
}

// ---------------------------------------------------------------------------
// part2 (round 11): per 256-row bucket, single-pass counting sort on the
// combined key (row*13 + colbucket):
//   stage edges in registers -> LDS histogram over 3328 keys -> per-row
//   serial scan + 256-wide block scan -> key cursors -> ONE scatter pass
//   into LDS image (=> per-row col-bucket-sorted) -> coalesced stream-out.
// ---------------------------------------------------------------------------
__global__ __launch_bounds__(256)
void part2_kernel(const int* __restrict__ bcur, const int2* __restrict__ part,
                  int* __restrict__ offs, int2* __restrict__ pce)
{
    __shared__ int scnt[256 * NCB];    // 13312 B: histogram, then cursors
    __shared__ int sdata[256];
    __shared__ int2 sout[BCAP];        // 36864 B staged output image
    const int b = blockIdx.x;
    const int tid = threadIdx.x;

    const int cnt = bcur[b];
    const int2* src = part + (size_t)b * BCAP;

    // stage this bucket's edges into registers (coalesced, strided by 256)
    int2 ed[EPT];
    #pragma unroll
    for (int j = 0; j < EPT; ++j) {
        const int idx = j * 256 + tid;
        ed[j] = (idx < cnt) ? src[idx] : make_int2(-1, 0);
    }

    // zero histogram
    #pragma unroll
    for (int j = 0; j < NCB; ++j) scnt[j * 256 + tid] = 0;

    // global prefix: gb = sum bcur[0..b-1]
    int partial = 0;
    for (int i = tid; i < b; i += 256) partial += bcur[i];
    sdata[tid] = partial;
    __syncthreads();
    #pragma unroll
    for (int off = 128; off > 0; off >>= 1) {
        if (tid < off) sdata[tid] += sdata[tid + off];
        __syncthreads();
    }
    const int gb = sdata[0];
    __syncthreads();

    // histogram over combined keys
    #pragma unroll
    for (int j = 0; j < EPT; ++j) {
        if (ed[j].x >= 0) {
            const int rl = ((u32)ed[j].x) >> 17;
            const int cb = (ed[j].x & 0x1FFFF) >> 13;
            atomicAdd(&scnt[rl * NCB + cb], 1);
        }
    }
    __syncthreads();

    // per-row serial sum (thread tid owns row tid) + block scan of row totals
    int rsum = 0;
    #pragma unroll
    for (int j = 0; j < NCB; ++j) rsum += scnt[tid * NCB + j];
    sdata[tid] = rsum;
    __syncthreads();
    #pragma unroll
    for (int off = 1; off < 256; off <<= 1) {
        const int val = (tid >= off) ? sdata[tid - off] : 0;
        __syncthreads();
        sdata[tid] += val;
        __syncthreads();
    }
    const int excl = sdata[tid] - rsum;
    offs[b * 256 + tid] = gb + excl;       // global CSR offset

    // convert histogram -> per-key cursors (exclusive scan within row)
    int run = excl;
    #pragma unroll
    for (int j = 0; j < NCB; ++j) {
        const int c = scnt[tid * NCB + j];
        scnt[tid * NCB + j] = run;
        run += c;
    }
    __syncthreads();

    // single scatter pass into LDS image (col-bucket-sorted within each row)
    #pragma unroll
    for (int j = 0; j < EPT; ++j) {
        if (ed[j].x >= 0) {
            const int rl  = ((u32)ed[j].x) >> 17;
            const int cb  = (ed[j].x & 0x1FFFF) >> 13;
            const int pos = atomicAdd(&scnt[rl * NCB + cb], 1);
            sout[pos] = make_int2(ed[j].x & 0x1FFFF, ed[j].y);
        }
    }
    __syncthreads();

    // coalesced stream-out
    #pragma unroll
    for (int j = 0; j < EPT; ++j) {
        const int idx = j * 256 + tid;
        if (idx < cnt) pce[(size_t)gb + idx] = sout[idx];
    }
}

// ---------------------------------------------------------------------------
// Gather helpers (bf16 rows, fp32 accumulate).
// ---------------------------------------------------------------------------
template<int LPC>
__device__ __forceinline__ void load_row(const u16* p, u32* u) {
    if constexpr (LPC == 8) {
        const uint4 t = *(const uint4*)p;
        u[0] = t.x; u[1] = t.y; u[2] = t.z; u[3] = t.w;
    } else {
        const uint2 t = *(const uint2*)p;
        u[0] = t.x; u[1] = t.y;
    }
}

template<int LPC>
__device__ __forceinline__ void fma_row(float v, const u32* u, float* a) {
    #pragma unroll
    for (int j = 0; j < LPC / 2; ++j) {
        a[2*j]   = fmaf(v, __uint_as_float(u[j] << 16),         a[2*j]);
        a[2*j+1] = fmaf(v, __uint_as_float(u[j] & 0xffff0000u), a[2*j+1]);
    }
}

// ---------------------------------------------------------------------------
// Fused SpMM+GEMM: gather 16 rows of A*t (4 edges in flight) ->
// relu(+residual) -> LDS A-tile -> mfma vs fragment-ordered Wf -> C store.
// MODE 1 also writes relu'd rows (h1) to Hout for the later residual.
// ---------------------------------------------------------------------------
template<int DO, int MODE>
__global__ __launch_bounds__(256)
void spmm_gemm(const int* __restrict__ offs, const int2* __restrict__ pce,
               const u16* __restrict__ Hb, const u16* __restrict__ Wf,
               const u16* __restrict__ Res, u16* __restrict__ Cb,
               u16* __restrict__ Hout)
{
    constexpr int RS   = 136;
    constexpr int PADW = DO + 8;
    __shared__ u16 smem[16 * 136];
    const int tid = threadIdx.x;
    const int ln  = tid & 15;
    const int rl  = tid >> 4;
    const int row = blockIdx.x * 16 + rl;

    const int s = offs[row];
    const int t = offs[row + 1];
    const u16* hbase = Hb + ln * 8;

    float a0[8], a1[8];
    #pragma unroll
    for (int j = 0; j < 8; ++j) { a0[j] = 0.f; a1[j] = 0.f; }

    int e = s;
    // 4 edges in flight: all loads issued before the FMA block (MLP).
    for (; e + 3 < t; e += 4) {
        const int2 E0 = pce[e];
        const int2 E1 = pce[e + 1];
        const int2 E2 = pce[e + 2];
        const int2 E3 = pce[e + 3];
        u32 u0[4], u1[4], u2[4], u3[4];
        load_row<8>(hbase + (size_t)E0.x * 128, u0);
        load_row<8>(hbase + (size_t)E1.x * 128, u1);
        load_row<8>(hbase + (size_t)E2.x * 128, u2);
        load_row<8>(hbase + (size_t)E3.x * 128, u3);
        fma_row<8>(__int_as_float(E0.y), u0, a0);
        fma_row<8>(__int_as_float(E1.y), u1, a1);
        fma_row<8>(__int_as_float(E2.y), u2, a0);
        fma_row<8>(__int_as_float(E3.y), u3, a1);
    }
    for (; e + 1 < t; e += 2) {
        const int2 E0 = pce[e];
        const int2 E1 = pce[e + 1];
        u32 u0[4], u1[4];
        load_row<8>(hbase + (size_t)E0.x * 128, u0);
        load_row<8>(hbase + (size_t)E1.x * 128, u1);
        fma_row<8>(__int_as_float(E0.y), u0, a0);
        fma_row<8>(__int_as_float(E1.y), u1, a1);
    }
    if (e < t) {
        const int2 E0 = pce[e];
        u32 u0[4];
        load_row<8>(hbase + (size_t)E0.x * 128, u0);
        fma_row<8>(__int_as_float(E0.y), u0, a0);
    }
    #pragma unroll
    for (int j = 0; j < 8; ++j) a0[j] = fmaxf(a0[j] + a1[j], 0.f);

    if constexpr (MODE == 2) {
        u32 r[4];
        load_row<8>(Res + (size_t)row * 128 + ln * 8, r);
        #pragma unroll
        for (int j = 0; j < 4; ++j) {
            a0[2*j]   += __uint_as_float(r[j] << 16);
            a0[2*j+1] += __uint_as_float(r[j] & 0xffff0000u);
        }
    }
    u32 o[4];
    #pragma unroll
    for (int j = 0; j < 4; ++j)
        o[j] = (u32)f2bf(a0[2*j]) | ((u32)f2bf(a0[2*j+1]) << 16);
    const uint4 packed = make_uint4(o[0], o[1], o[2], o[3]);
    *(uint4*)&smem[rl * RS + ln * 8] = packed;
    if constexpr (MODE == 1)
        *(uint4*)(Hout + (size_t)row * 128 + ln * 8) = packed;
    __syncthreads();

    constexpr int TPW = DO / 64;
    const int w    = tid >> 6;
    const int lane = tid & 63;
    const int m    = lane & 15;
    const int q    = lane >> 4;

    bf16x8 afrag[4];
    #pragma unroll
    for (int kc = 0; kc < 4; ++kc)
        afrag[kc] = *(const bf16x8*)&smem[m * RS + kc * 32 + q * 8];

    f32x4 acc[TPW];
    #pragma unroll
    for (int tw = 0; tw < TPW; ++tw) {
        const int ct = w * TPW + tw;
        acc[tw] = (f32x4){0.f, 0.f, 0.f, 0.f};
        #pragma unroll
        for (int kc = 0; kc < 4; ++kc) {
            const bf16x8 b = *(const bf16x8*)(Wf + (((ct * 4 + kc) * 64) + lane) * 8);
            acc[tw] = __builtin_amdgcn_mfma_f32_16x16x32_bf16(afrag[kc], b, acc[tw], 0, 0, 0);
        }
    }
    __syncthreads();

    #pragma unroll
    for (int tw = 0; tw < TPW; ++tw) {
        const int ct = w * TPW + tw;
        #pragma unroll
        for (int r = 0; r < 4; ++r)
            smem[(q * 4 + r) * PADW + ct * 16 + m] = f2bf(acc[tw][r]);
    }
    __syncthreads();

    if (DO == 128 || tid < 128) {
        const int g = tid * 8;
        const int r = g / DO;
        const int c = g % DO;
        const int4 v = *(const int4*)&smem[r * PADW + c];
        *(int4*)(Cb + ((size_t)blockIdx.x * 16 + r) * DO + c) = v;
    }
}

// ---------------------------------------------------------------------------
// Final CSR SpMM (layer 3): gather t2 (D=64), 4 edges in flight, fp32 out.
// ---------------------------------------------------------------------------
__global__ __launch_bounds__(256)
void spmm_out(const int* __restrict__ offs, const int2* __restrict__ pce,
              const u16* __restrict__ Hb, float* __restrict__ Y)
{
    const int ln  = threadIdx.x & 15;
    const int row = blockIdx.x * 16 + (threadIdx.x >> 4);
    if (row >= NN) return;
    const int s = offs[row];
    const int t = offs[row + 1];
    const u16* hbase = Hb + ln * 4;

    float a0[4], a1[4];
    #pragma unroll
    for (int j = 0; j < 4; ++j) { a0[j] = 0.f; a1[j] = 0.f; }

    int e = s;
    for (; e + 3 < t; e += 4) {
        const int2 E0 = pce[e];
        const int2 E1 = pce[e + 1];
        const int2 E2 = pce[e + 2];
        const int2 E3 = pce[e + 3];
        u32 u0[2], u1[2], u2[2], u3[2];
        load_row<4>(hbase + (size_t)E0.x * 64, u0);
        load_row<4>(hbase + (size_t)E1.x * 64, u1);
        load_row<4>(hbase + (size_t)E2.x * 64, u2);
        load_row<4>(hbase + (size_t)E3.x * 64, u3);
        fma_row<4>(__int_as_float(E0.y), u0, a0);
        fma_row<4>(__int_as_float(E1.y), u1, a1);
        fma_row<4>(__int_as_float(E2.y), u2, a0);
        fma_row<4>(__int_as_float(E3.y), u3, a1);
    }
    for (; e + 1 < t; e += 2) {
        const int2 E0 = pce[e];
        const int2 E1 = pce[e + 1];
        u32 u0[2], u1[2];
        load_row<4>(hbase + (size_t)E0.x * 64, u0);
        load_row<4>(hbase + (size_t)E1.x * 64, u1);
        fma_row<4>(__int_as_float(E0.y), u0, a0);
        fma_row<4>(__int_as_float(E1.y), u1, a1);
    }
    if (e < t) {
        const int2 E0 = pce[e];
        u32 u0[2];
        load_row<4>(hbase + (size_t)E0.x * 64, u0);
        fma_row<4>(__int_as_float(E0.y), u0, a0);
    }
    #pragma unroll
    for (int j = 0; j < 4; ++j) a0[j] += a1[j];
    *(float4*)(Y + (size_t)row * 64 + ln * 4) = make_float4(a0[0], a0[1], a0[2], a0[3]);
}

extern "C" void kernel_launch(void* const* d_in, const int* in_sizes, int n_in,
                              void* d_out, int out_size, void* d_ws, size_t ws_size,
                              hipStream_t stream) {
    const float* x    = (const float*)d_in[0];
    const int*   erow = (const int*)  d_in[1];
    const int*   ecol = (const int*)  d_in[2];
    const float* eval = (const float*)d_in[3];
    const float* W0   = (const float*)d_in[4];
    const float* W1   = (const float*)d_in[5];
    const float* W2   = (const float*)d_in[6];
    float* out = (float*)d_out;

    char* p = (char*)d_ws;
    const size_t BUFB = (size_t)NN * 128 * sizeof(u16);   // 25.6 MB
    u16* t0b  = (u16*)p;  p += BUFB;     // t0; reused for t2 (t0 dead by then)
    u16* t1b  = (u16*)p;  p += BUFB;
    u16* h1b  = (u16*)p;  p += BUFB;
    u16* wf0  = (u16*)p;  p += 128 * 128 * 2;
    u16* wf1  = (u16*)p;  p += 128 * 128 * 2;
    u16* wf2  = (u16*)p;  p += 64 * 128 * 2;
    int* bcur   = (int*)p; p += 512 * 4;
    int* offs   = (int*)p; p += ((size_t)PAD + 256) * 4;
    int2* part  = (int2*)p; p += (size_t)NBUCK * BCAP * 8;  // 14.45 MB
    int2* pce   = (int2*)p;                                 // 12.8 MB

    const dim3 blk(256);
    const int rowBlocks = NN / 16;     // 6250

    // wcvt (also zeroes bcur) -> K1 [part1 || gemm0] -> part2 -> F1 -> F2 -> out
    wcvt_kernel<<<64, blk, 0, stream>>>(W0, W1, W2, wf0, wf1, wf2, bcur);
    k1_kernel  <<<P1B + G0B, blk, 0, stream>>>(x, wf0, t0b, erow, ecol, eval, bcur, part);
    part2_kernel<<<NBUCK, blk, 0, stream>>>(bcur, part, offs, pce);
    spmm_gemm<128, 1><<<rowBlocks, blk, 0, stream>>>(offs, pce, t0b, wf1, nullptr, t1b, h1b);
    spmm_gemm<64, 2><<<rowBlocks, blk, 0, stream>>>(offs, pce, t1b, wf2, h1b, t0b, nullptr);
    spmm_out<<<rowBlocks, blk, 0, stream>>>(offs, pce, t0b, out);
}

// Round 3
// 315.606 us; speedup vs baseline: 1.1322x; 1.0433x over previous
//
#include <hip/hip_runtime.h>

// GCN on MI355X (gfx950). n=100000, 1.6M edges, D 128/128/64.
// Round 12: cooperative pce load + shfl broadcast in the gather kernels.
//  - Evidence: F1/F2 pinned at ~3.3 TB/s L2-miss traffic across 3 rounds with
//    FETCH at the structural floor (~180 MB = each XCD touches ~90% of H's
//    lines once) -> scattered-line fabric ceiling. MLP unroll was null.
//  - Remaining lever for latency-limited kernels (spmm_out, and any slack in
//    F1/F2): remove serial pce->row round trips. The 16 lanes of a row-group
//    now load the row's next 16 pce entries in ONE coalesced 128B load, then
//    __shfl(width=16)-broadcast each edge's (col,val); row loads issue
//    back-to-back with no interleaved pce trips (8 -> ~5 serial trips/row).
//  - OOB edge slots have (col,val)=(0,0): harmless read of row 0, adds 0.
// Pipeline: wcvt -> K1[part1||gemm0] -> part2 -> F1 -> F2 -> spmm_out.

typedef unsigned int u32;
typedef unsigned short u16;
typedef __attribute__((ext_vector_type(8))) short bf16x8;
typedef __attribute__((ext_vector_type(4))) float f32x4;

constexpr int NN = 100000;
constexpr int NE = 1600000;
constexpr int PAD = 100352;            // 392 * 256
constexpr int NBUCK = 392;             // buckets of 256 rows
constexpr int BCAP = 4608;             // per-bucket capacity (mean 4082, +8 sigma)
constexpr int EPB = 4096;              // edges per part1 block
constexpr int P1B = (NE + EPB - 1) / EPB;   // 391 part1 blocks
constexpr int G0B = (NN + 63) / 64;         // 1563 gemm0 blocks
constexpr int EPT = BCAP / 256;        // 18 edges staged per thread in part2
constexpr int NCB = 13;                // col buckets of 8192 (99999>>13 = 12)

__device__ __forceinline__ u16 f2bf(float f) {   // RNE round to bf16
    u32 x = __float_as_uint(f);
    x += 0x7fffu + ((x >> 16) & 1u);
    return (u16)(x >> 16);
}

// ---------------------------------------------------------------------------
// Weight fp32 -> bf16 in B-fragment order; also zeroes bcur.
// ---------------------------------------------------------------------------
__device__ __forceinline__ void wfrag_one(const float* __restrict__ W,
                                          u16* __restrict__ Wf, int total, int i)
{
    if (i < total) {
        const int j    = i & 7;
        const int lane = (i >> 3) & 63;
        const int kc   = (i >> 9) & 3;
        const int ct   = i >> 11;
        const int src  = (ct * 16 + (lane & 15)) * 128 + kc * 32 + (lane >> 4) * 8 + j;
        Wf[i] = f2bf(W[src]);
    }
}

__global__ __launch_bounds__(256)
void wcvt_kernel(const float* __restrict__ W0, const float* __restrict__ W1,
                 const float* __restrict__ W2, u16* __restrict__ wf0,
                 u16* __restrict__ wf1, u16* __restrict__ wf2,
                 int* __restrict__ bcur)
{
    const int i = blockIdx.x * 256 + threadIdx.x;
    if (i < 512) bcur[i] = 0;
    wfrag_one(W0, wf0, 128 * 128, i);
    wfrag_one(W1, wf1, 128 * 128, i);
    wfrag_one(W2, wf2, 64 * 128, i);
}

// ---------------------------------------------------------------------------
// K1: blocks [0, P1B) = part1 (bucket partition, streaming two-pass);
//     blocks [P1B, P1B+G0B) = gemm0 (t0 = x @ W0^T, bf16 MFMA).
// Shared LDS buffer sized for the gemm branch (17408 B).
// ---------------------------------------------------------------------------
__global__ __launch_bounds__(256)
void k1_kernel(const float* __restrict__ x, const u16* __restrict__ Wf,
               u16* __restrict__ Cb,
               const int* __restrict__ erow, const int* __restrict__ ecol,
               const float* __restrict__ eval, int* __restrict__ bcur,
               int2* __restrict__ part)
{
    __shared__ u16 smem[64 * 136];     // gemm: sA/sC; part1: shist/sbase
    const int tid = threadIdx.x;

    if ((int)blockIdx.x < P1B) {
        // ---------------- part1 branch ----------------
        int* shist = (int*)smem;
        int* sbase = shist + NBUCK;
        for (int i = tid; i < NBUCK; i += 256) shist[i] = 0;
        __syncthreads();

        const int base = blockIdx.x * EPB;
        #pragma unroll
        for (int j = 0; j < EPB / 256; ++j) {
            const int e = base + j * 256 + tid;
            if (e < NE) atomicAdd(&shist[erow[e] >> 8], 1);
        }
        __syncthreads();
        for (int i = tid; i < NBUCK; i += 256) {
            const int c = shist[i];
            sbase[i] = c ? atomicAdd(&bcur[i], c) : 0;
            shist[i] = 0;
        }
        __syncthreads();
        #pragma unroll
        for (int j = 0; j < EPB / 256; ++j) {
            const int e = base + j * 256 + tid;
            if (e < NE) {
                const int r = erow[e];
                const int b = r >> 8;
                const int rk = atomicAdd(&shist[b], 1);
                part[(size_t)b * BCAP + sbase[b] + rk] =
                    make_int2(((r & 255) << 17) | ecol[e], __float_as_int(eval[e]));
            }
        }
        return;
    }

    // ---------------- gemm0 branch ----------------
    constexpr int RS   = 136;
    constexpr int PADW = 136;          // DO=128 + 8
    u16* sA = smem;
    u16* sC = smem;
    const int w    = tid >> 6;
    const int lane = tid & 63;
    const int m    = lane & 15;
    const int q    = lane >> 4;
    const int rowBase = ((int)blockIdx.x - P1B) * 64;

    #pragma unroll
    for (int i = 0; i < 8; ++i) {
        const int g = (i * 256 + tid) * 4;
        const int r = g >> 7, c = g & 127;
        float4 v = make_float4(0.f, 0.f, 0.f, 0.f);
        if (rowBase + r < NN) v = *(const float4*)(x + (size_t)(rowBase + r) * 128 + c);
        u16* d = &sA[r * RS + c];
        d[0] = f2bf(v.x); d[1] = f2bf(v.y); d[2] = f2bf(v.z); d[3] = f2bf(v.w);
    }
    __syncthreads();

    bf16x8 afrag[4];
    #pragma unroll
    for (int kc = 0; kc < 4; ++kc)
        afrag[kc] = *(const bf16x8*)&sA[(w * 16 + m) * RS + kc * 32 + q * 8];
    __syncthreads();

    #pragma unroll
    for (int ct = 0; ct < 8; ++ct) {
        f32x4 acc = {0.f, 0.f, 0.f, 0.f};
        #pragma unroll
        for (int kc = 0; kc < 4; ++kc) {
            const bf16x8 b = *(const bf16x8*)(Wf + (((ct * 4 + kc) * 64) + lane) * 8);
            acc = __builtin_amdgcn_mfma_f32_16x16x32_bf16(afrag[kc], b, acc, 0, 0, 0);
        }
        #pragma unroll
        for (int r = 0; r < 4; ++r)
            sC[(w * 16 + q * 4 + r) * PADW + ct * 16 + m] = f2bf(acc[r]);
    }
    __syncthreads();

    const int g    = lane >> 2;
    const int cb   = (lane & 3) * 32;
    const int grow = rowBase + w * 16 + g;
    if (grow < NN) {
        #pragma unroll
        for (int i = 0; i < 4; ++i) {
            const int4 v = *(const int4*)&sC[(w * 16 + g) * PADW + cb + i * 8];
            *(int4*)(Cb + (size_t)grow * 128 + cb + i * 8) = v;
        }
    }
}

// ---------------------------------------------------------------------------
// part2: per 256-row bucket, single-pass counting sort on the combined key
// (row*13 + colbucket) -> per-row col-bucket-sorted CSR, coalesced stream-out.
// ---------------------------------------------------------------------------
__global__ __launch_bounds__(256)
void part2_kernel(const int* __restrict__ bcur, const int2* __restrict__ part,
                  int* __restrict__ offs, int2* __restrict__ pce)
{
    __shared__ int scnt[256 * NCB];    // 13312 B: histogram, then cursors
    __shared__ int sdata[256];
    __shared__ int2 sout[BCAP];        // 36864 B staged output image
    const int b = blockIdx.x;
    const int tid = threadIdx.x;

    const int cnt = bcur[b];
    const int2* src = part + (size_t)b * BCAP;

    // stage this bucket's edges into registers (coalesced, strided by 256)
    int2 ed[EPT];
    #pragma unroll
    for (int j = 0; j < EPT; ++j) {
        const int idx = j * 256 + tid;
        ed[j] = (idx < cnt) ? src[idx] : make_int2(-1, 0);
    }

    // zero histogram
    #pragma unroll
    for (int j = 0; j < NCB; ++j) scnt[j * 256 + tid] = 0;

    // global prefix: gb = sum bcur[0..b-1]
    int partial = 0;
    for (int i = tid; i < b; i += 256) partial += bcur[i];
    sdata[tid] = partial;
    __syncthreads();
    #pragma unroll
    for (int off = 128; off > 0; off >>= 1) {
        if (tid < off) sdata[tid] += sdata[tid + off];
        __syncthreads();
    }
    const int gb = sdata[0];
    __syncthreads();

    // histogram over combined keys
    #pragma unroll
    for (int j = 0; j < EPT; ++j) {
        if (ed[j].x >= 0) {
            const int rl = ((u32)ed[j].x) >> 17;
            const int cb = (ed[j].x & 0x1FFFF) >> 13;
            atomicAdd(&scnt[rl * NCB + cb], 1);
        }
    }
    __syncthreads();

    // per-row serial sum (thread tid owns row tid) + block scan of row totals
    int rsum = 0;
    #pragma unroll
    for (int j = 0; j < NCB; ++j) rsum += scnt[tid * NCB + j];
    sdata[tid] = rsum;
    __syncthreads();
    #pragma unroll
    for (int off = 1; off < 256; off <<= 1) {
        const int val = (tid >= off) ? sdata[tid - off] : 0;
        __syncthreads();
        sdata[tid] += val;
        __syncthreads();
    }
    const int excl = sdata[tid] - rsum;
    offs[b * 256 + tid] = gb + excl;       // global CSR offset

    // convert histogram -> per-key cursors (exclusive scan within row)
    int run = excl;
    #pragma unroll
    for (int j = 0; j < NCB; ++j) {
        const int c = scnt[tid * NCB + j];
        scnt[tid * NCB + j] = run;
        run += c;
    }
    __syncthreads();

    // single scatter pass into LDS image (col-bucket-sorted within each row)
    #pragma unroll
    for (int j = 0; j < EPT; ++j) {
        if (ed[j].x >= 0) {
            const int rl  = ((u32)ed[j].x) >> 17;
            const int cb  = (ed[j].x & 0x1FFFF) >> 13;
            const int pos = atomicAdd(&scnt[rl * NCB + cb], 1);
            sout[pos] = make_int2(ed[j].x & 0x1FFFF, ed[j].y);
        }
    }
    __syncthreads();

    // coalesced stream-out
    #pragma unroll
    for (int j = 0; j < EPT; ++j) {
        const int idx = j * 256 + tid;
        if (idx < cnt) pce[(size_t)gb + idx] = sout[idx];
    }
}

// ---------------------------------------------------------------------------
// Gather helpers (bf16 rows, fp32 accumulate).
// ---------------------------------------------------------------------------
template<int LPC>
__device__ __forceinline__ void load_row(const u16* p, u32* u) {
    if constexpr (LPC == 8) {
        const uint4 t = *(const uint4*)p;
        u[0] = t.x; u[1] = t.y; u[2] = t.z; u[3] = t.w;
    } else {
        const uint2 t = *(const uint2*)p;
        u[0] = t.x; u[1] = t.y;
    }
}

template<int LPC>
__device__ __forceinline__ void fma_row(float v, const u32* u, float* a) {
    #pragma unroll
    for (int j = 0; j < LPC / 2; ++j) {
        a[2*j]   = fmaf(v, __uint_as_float(u[j] << 16),         a[2*j]);
        a[2*j+1] = fmaf(v, __uint_as_float(u[j] & 0xffff0000u), a[2*j+1]);
    }
}

// ---------------------------------------------------------------------------
// Fused SpMM+GEMM: cooperative pce window load (16 edges / one 128B load per
// group) + shfl(16) broadcast -> 4-edge quads of back-to-back row loads ->
// relu(+residual) -> LDS A-tile -> mfma vs fragment-ordered Wf -> C store.
// MODE 1 also writes relu'd rows (h1) to Hout for the later residual.
// ---------------------------------------------------------------------------
template<int DO, int MODE>
__global__ __launch_bounds__(256)
void spmm_gemm(const int* __restrict__ offs, const int2* __restrict__ pce,
               const u16* __restrict__ Hb, const u16* __restrict__ Wf,
               const u16* __restrict__ Res, u16* __restrict__ Cb,
               u16* __restrict__ Hout)
{
    constexpr int RS   = 136;
    constexpr int PADW = DO + 8;
    __shared__ u16 smem[16 * 136];
    const int tid = threadIdx.x;
    const int ln  = tid & 15;
    const int rl  = tid >> 4;
    const int row = blockIdx.x * 16 + rl;

    const int s = offs[row];
    const int t = offs[row + 1];
    const u16* hbase = Hb + ln * 8;

    float a0[8], a1[8];
    #pragma unroll
    for (int j = 0; j < 8; ++j) { a0[j] = 0.f; a1[j] = 0.f; }

    for (int e = s; e < t; e += 16) {
        // cooperative load of this row's next 16 edges (one int2 per lane)
        int2 my = make_int2(0, 0);
        if (e + ln < t) my = pce[e + ln];
        const int rem = t - e;
        #pragma unroll
        for (int qd = 0; qd < 4; ++qd) {
            if (qd * 4 < rem) {
                const int c0 = __shfl(my.x, qd * 4 + 0, 16);
                const int v0 = __shfl(my.y, qd * 4 + 0, 16);
                const int c1 = __shfl(my.x, qd * 4 + 1, 16);
                const int v1 = __shfl(my.y, qd * 4 + 1, 16);
                const int c2 = __shfl(my.x, qd * 4 + 2, 16);
                const int v2 = __shfl(my.y, qd * 4 + 2, 16);
                const int c3 = __shfl(my.x, qd * 4 + 3, 16);
                const int v3 = __shfl(my.y, qd * 4 + 3, 16);
                u32 u0[4], u1[4], u2[4], u3[4];
                load_row<8>(hbase + (size_t)c0 * 128, u0);
                load_row<8>(hbase + (size_t)c1 * 128, u1);
                load_row<8>(hbase + (size_t)c2 * 128, u2);
                load_row<8>(hbase + (size_t)c3 * 128, u3);
                fma_row<8>(__int_as_float(v0), u0, a0);
                fma_row<8>(__int_as_float(v1), u1, a1);
                fma_row<8>(__int_as_float(v2), u2, a0);
                fma_row<8>(__int_as_float(v3), u3, a1);
            }
        }
    }
    #pragma unroll
    for (int j = 0; j < 8; ++j) a0[j] = fmaxf(a0[j] + a1[j], 0.f);

    if constexpr (MODE == 2) {
        u32 r[4];
        load_row<8>(Res + (size_t)row * 128 + ln * 8, r);
        #pragma unroll
        for (int j = 0; j < 4; ++j) {
            a0[2*j]   += __uint_as_float(r[j] << 16);
            a0[2*j+1] += __uint_as_float(r[j] & 0xffff0000u);
        }
    }
    u32 o[4];
    #pragma unroll
    for (int j = 0; j < 4; ++j)
        o[j] = (u32)f2bf(a0[2*j]) | ((u32)f2bf(a0[2*j+1]) << 16);
    const uint4 packed = make_uint4(o[0], o[1], o[2], o[3]);
    *(uint4*)&smem[rl * RS + ln * 8] = packed;
    if constexpr (MODE == 1)
        *(uint4*)(Hout + (size_t)row * 128 + ln * 8) = packed;
    __syncthreads();

    constexpr int TPW = DO / 64;
    const int w    = tid >> 6;
    const int lane = tid & 63;
    const int m    = lane & 15;
    const int q    = lane >> 4;

    bf16x8 afrag[4];
    #pragma unroll
    for (int kc = 0; kc < 4; ++kc)
        afrag[kc] = *(const bf16x8*)&smem[m * RS + kc * 32 + q * 8];

    f32x4 acc[TPW];
    #pragma unroll
    for (int tw = 0; tw < TPW; ++tw) {
        const int ct = w * TPW + tw;
        acc[tw] = (f32x4){0.f, 0.f, 0.f, 0.f};
        #pragma unroll
        for (int kc = 0; kc < 4; ++kc) {
            const bf16x8 b = *(const bf16x8*)(Wf + (((ct * 4 + kc) * 64) + lane) * 8);
            acc[tw] = __builtin_amdgcn_mfma_f32_16x16x32_bf16(afrag[kc], b, acc[tw], 0, 0, 0);
        }
    }
    __syncthreads();

    #pragma unroll
    for (int tw = 0; tw < TPW; ++tw) {
        const int ct = w * TPW + tw;
        #pragma unroll
        for (int r = 0; r < 4; ++r)
            smem[(q * 4 + r) * PADW + ct * 16 + m] = f2bf(acc[tw][r]);
    }
    __syncthreads();

    if (DO == 128 || tid < 128) {
        const int g = tid * 8;
        const int r = g / DO;
        const int c = g % DO;
        const int4 v = *(const int4*)&smem[r * PADW + c];
        *(int4*)(Cb + ((size_t)blockIdx.x * 16 + r) * DO + c) = v;
    }
}

// ---------------------------------------------------------------------------
// Final CSR SpMM (layer 3): gather t2 (D=64), cooperative pce + shfl, fp32 out.
// ---------------------------------------------------------------------------
__global__ __launch_bounds__(256)
void spmm_out(const int* __restrict__ offs, const int2* __restrict__ pce,
              const u16* __restrict__ Hb, float* __restrict__ Y)
{
    const int ln  = threadIdx.x & 15;
    const int row = blockIdx.x * 16 + (threadIdx.x >> 4);
    if (row >= NN) return;
    const int s = offs[row];
    const int t = offs[row + 1];
    const u16* hbase = Hb + ln * 4;

    float a0[4], a1[4];
    #pragma unroll
    for (int j = 0; j < 4; ++j) { a0[j] = 0.f; a1[j] = 0.f; }

    for (int e = s; e < t; e += 16) {
        int2 my = make_int2(0, 0);
        if (e + ln < t) my = pce[e + ln];
        const int rem = t - e;
        #pragma unroll
        for (int qd = 0; qd < 4; ++qd) {
            if (qd * 4 < rem) {
                const int c0 = __shfl(my.x, qd * 4 + 0, 16);
                const int v0 = __shfl(my.y, qd * 4 + 0, 16);
                const int c1 = __shfl(my.x, qd * 4 + 1, 16);
                const int v1 = __shfl(my.y, qd * 4 + 1, 16);
                const int c2 = __shfl(my.x, qd * 4 + 2, 16);
                const int v2 = __shfl(my.y, qd * 4 + 2, 16);
                const int c3 = __shfl(my.x, qd * 4 + 3, 16);
                const int v3 = __shfl(my.y, qd * 4 + 3, 16);
                u32 u0[2], u1[2], u2[2], u3[2];
                load_row<4>(hbase + (size_t)c0 * 64, u0);
                load_row<4>(hbase + (size_t)c1 * 64, u1);
                load_row<4>(hbase + (size_t)c2 * 64, u2);
                load_row<4>(hbase + (size_t)c3 * 64, u3);
                fma_row<4>(__int_as_float(v0), u0, a0);
                fma_row<4>(__int_as_float(v1), u1, a1);
                fma_row<4>(__int_as_float(v2), u2, a0);
                fma_row<4>(__int_as_float(v3), u3, a1);
            }
        }
    }
    #pragma unroll
    for (int j = 0; j < 4; ++j) a0[j] += a1[j];
    *(float4*)(Y + (size_t)row * 64 + ln * 4) = make_float4(a0[0], a0[1], a0[2], a0[3]);
}

extern "C" void kernel_launch(void* const* d_in, const int* in_sizes, int n_in,
                              void* d_out, int out_size, void* d_ws, size_t ws_size,
                              hipStream_t stream) {
    const float* x    = (const float*)d_in[0];
    const int*   erow = (const int*)  d_in[1];
    const int*   ecol = (const int*)  d_in[2];
    const float* eval = (const float*)d_in[3];
    const float* W0   = (const float*)d_in[4];
    const float* W1   = (const float*)d_in[5];
    const float* W2   = (const float*)d_in[6];
    float* out = (float*)d_out;

    char* p = (char*)d_ws;
    const size_t BUFB = (size_t)NN * 128 * sizeof(u16);   // 25.6 MB
    u16* t0b  = (u16*)p;  p += BUFB;     // t0; reused for t2 (t0 dead by then)
    u16* t1b  = (u16*)p;  p += BUFB;
    u16* h1b  = (u16*)p;  p += BUFB;
    u16* wf0  = (u16*)p;  p += 128 * 128 * 2;
    u16* wf1  = (u16*)p;  p += 128 * 128 * 2;
    u16* wf2  = (u16*)p;  p += 64 * 128 * 2;
    int* bcur   = (int*)p; p += 512 * 4;
    int* offs   = (int*)p; p += ((size_t)PAD + 256) * 4;
    int2* part  = (int2*)p; p += (size_t)NBUCK * BCAP * 8;  // 14.45 MB
    int2* pce   = (int2*)p;                                 // 12.8 MB

    const dim3 blk(256);
    const int rowBlocks = NN / 16;     // 6250

    // wcvt (also zeroes bcur) -> K1 [part1 || gemm0] -> part2 -> F1 -> F2 -> out
    wcvt_kernel<<<64, blk, 0, stream>>>(W0, W1, W2, wf0, wf1, wf2, bcur);
    k1_kernel  <<<P1B + G0B, blk, 0, stream>>>(x, wf0, t0b, erow, ecol, eval, bcur, part);
    part2_kernel<<<NBUCK, blk, 0, stream>>>(bcur, part, offs, pce);
    spmm_gemm<128, 1><<<rowBlocks, blk, 0, stream>>>(offs, pce, t0b, wf1, nullptr, t1b, h1b);
    spmm_gemm<64, 2><<<rowBlocks, blk, 0, stream>>>(offs, pce, t1b, wf2, h1b, t0b, nullptr);
    spmm_out<<<rowBlocks, blk, 0, stream>>>(offs, pce, t0b, out);
}